// Round 6
// baseline (98.722 us; speedup 1.0000x reference)
//
#include <hip/hip_runtime.h>

// LateralEI: out = GAIN * rownorm(K) @ h, K = 0.8*exp(-d2/0.72) - exp(-d2/2.88)
// z: [8192][2] f32, h: [8192][128] f32, out: [8192][128] f32
//
// R6 = R5 with the LDS-DMA race fixed. R5's hand vmcnt(10) assumed an issue
// order the scheduler didn't preserve (in-loop z global loads reordered vs
// produce loads -> slot consumed before its DMA landed). R6 makes the count
// deterministic: the K-loop's ONLY vmem ops are the 4 produce loads/iter
// (z/az staged to LDS in the preamble, read via quad-uniform ds_read), so
// `s_waitcnt vmcnt(4)` provably drains produce(it) and leaves produce(it+1)
// in flight across the raw s_barrier. 2 waves share a depth-3 8KB ring:
// each wave drains its own half pre-barrier; slot (it+1)%3 was last read
// >=2 barriers ago (WAR-safe).

typedef float f32x4 __attribute__((ext_vector_type(4)));
typedef short s16x8 __attribute__((ext_vector_type(8)));
typedef unsigned int u32x4 __attribute__((ext_vector_type(4)));

#define NPTS 8192
#define DH 128
#define A_I (-0.5009357781f)  // -log2(e)/(2*1.2^2); A_E = 4*A_I
#define GAIN_C 0.05f

#define NKS 8        // cross-block K-slices (1024 k each)
#define NITER 32     // iters per block: 1024 k / 32
#define NRT 128      // row-tiles (64 rows each)

// ---------- pre-pass: h [8192][128] f32 -> hTf fragment-major bf16 (R4-verified) ----------
// Fragment (k5=k>>5, cf): 512 halfwords at hTf[(k5*8+cf)*512], chunk for lane
// (q=lane>>4, nf=lane&15) at +lane*8: h[k5*32+q*8+j][cf*16+nf], j=0..7.
__global__ __launch_bounds__(256) void h_to_hTf(
    const float* __restrict__ h, unsigned short* __restrict__ hTf) {
  __shared__ unsigned int tileW[DH * 17];  // [n][kp], kp = k-pair 0..15
  const int t = threadIdx.x;
  const int k5 = blockIdx.x;
  const int n = t & 127;
  const int g = t >> 7;  // 0..1
#pragma unroll
  for (int p = 0; p < 8; ++p) {
    const int kp = g * 8 + p;
    unsigned int a = __float_as_uint(h[(k5 * 32 + 2 * kp) * DH + n]);
    unsigned int b = __float_as_uint(h[(k5 * 32 + 2 * kp + 1) * DH + n]);
    a = (a + 0x7fffu + ((a >> 16) & 1u)) >> 16;          // RNE low half
    b = (b + 0x7fffu + ((b >> 16) & 1u)) & 0xffff0000u;  // RNE high half
    tileW[n * 17 + kp] = a | b;
  }
  __syncthreads();
#pragma unroll
  for (int it = 0; it < 2; ++it) {
    const int u = t + it * 256;
    const int cf = u >> 6;
    const int lane = u & 63;
    const int nf = lane & 15;
    const int q = lane >> 4;
    const int n2 = cf * 16 + nf;
    u32x4 val;
#pragma unroll
    for (int i = 0; i < 4; ++i) val[i] = tileW[n2 * 17 + q * 4 + i];
    *(u32x4*)(hTf + k5 * 4096 + u * 8) = val;
  }
}

// stage one 8KB iter-tile into a ring slot (per-thread 4 x 16B, 128 threads)
__device__ __forceinline__ void produce_tile(const char* src, char* dst, int t) {
#pragma unroll
  for (int c = 0; c < 4; ++c)
    __builtin_amdgcn_global_load_lds(
        (const __attribute__((address_space(1))) unsigned int*)(src + c * 2048 + t * 16),
        (__attribute__((address_space(3))) unsigned int*)(dst + c * 2048 + t * 16),
        16, 0, 0);
}

// ---------- main fused kernel ----------
__global__ __launch_bounds__(128, 2) void lateral_ei_main(
    const float* __restrict__ z, const unsigned short* __restrict__ hTf,
    unsigned short* __restrict__ partb, float* __restrict__ prs) {
  __shared__ __align__(16) unsigned short ring[3][4096];  // 3 x 8KB
  __shared__ __align__(16) float zxy[2048];               // (x,y) per k, 8KB... 1024 k
  __shared__ __align__(16) float zaz[1024];               // A_I*|z_k|^2

  const int t = threadIdx.x;
  const int lane = t & 63;
  const int w = t >> 6;  // 0..1
  const int rt = blockIdx.x & (NRT - 1);
  const int ks = blockIdx.x >> 7;  // 0..NKS-1
  const int i0 = rt * 64 + w * 32;
  const int nf = lane & 15;
  const int q = lane >> 4;
  const int k0 = ks * (NPTS / NKS);  // 1024-k slice

  // zi constants for rows i0+nf, i0+16+nf
  const float zx0 = z[(i0 + nf) * 2], zy0 = z[(i0 + nf) * 2 + 1];
  const float zx1 = z[(i0 + 16 + nf) * 2], zy1 = z[(i0 + 16 + nf) * 2 + 1];
  const float cA0 = A_I * (zx0 * zx0 + zy0 * zy0);
  const float cA1 = A_I * (zx1 * zx1 + zy1 * zy1);
  const float cX0 = -2.f * A_I * zx0, cY0 = -2.f * A_I * zy0;
  const float cX1 = -2.f * A_I * zx1, cY1 = -2.f * A_I * zy1;

  const char* srcB = (const char*)hTf + (size_t)(ks * 32) * 8192;
  char* ringB = (char*)&ring[0][0];

  // ---- preamble: stage iter-0 B tile; stage z/az slice into LDS ----
  produce_tile(srcB, ringB, t);
#pragma unroll
  for (int pp = 0; pp < 2; ++pp) {
    const int kk = (t + pp * 128) * 4;  // 4 k's per thread per pass
    const f32x4 p01 = *(const f32x4*)(z + (size_t)(k0 + kk) * 2);
    const f32x4 p23 = *(const f32x4*)(z + (size_t)(k0 + kk) * 2 + 4);
    *(f32x4*)(zxy + kk * 2) = p01;
    *(f32x4*)(zxy + kk * 2 + 4) = p23;
    f32x4 az;
    az[0] = A_I * fmaf(p01[1], p01[1], p01[0] * p01[0]);
    az[1] = A_I * fmaf(p01[3], p01[3], p01[2] * p01[2]);
    az[2] = A_I * fmaf(p23[1], p23[1], p23[0] * p23[0]);
    az[3] = A_I * fmaf(p23[3], p23[3], p23[2] * p23[2]);
    *(f32x4*)(zaz + kk) = az;
  }
  __syncthreads();  // drains preamble vmem (incl. produce(0)) + LDS writes

  // iter-0 z into regs (quad-uniform LDS broadcast reads)
  const int kq = q * 8;
  f32x4 zc0 = *(const f32x4*)(zxy + kq * 2);
  f32x4 zc1 = *(const f32x4*)(zxy + kq * 2 + 4);
  f32x4 zc2 = *(const f32x4*)(zxy + kq * 2 + 8);
  f32x4 zc3 = *(const f32x4*)(zxy + kq * 2 + 12);
  f32x4 az0 = *(const f32x4*)(zaz + kq);
  f32x4 az1 = *(const f32x4*)(zaz + kq + 4);

  f32x4 acc0[8], acc1[8];
#pragma unroll
  for (int cf = 0; cf < 8; ++cf) {
    acc0[cf] = (f32x4){0.f, 0.f, 0.f, 0.f};
    acc1[cf] = (f32x4){0.f, 0.f, 0.f, 0.f};
  }
  float rs0 = 0.f, rs1 = 0.f;

  int sc = 0;  // consume slot = it % 3
#pragma unroll 1
  for (int it = 0; it < NITER; ++it) {
    const int sp = (sc == 2) ? 0 : sc + 1;   // slot for it+1
    const int nit = (it + 1) & (NITER - 1);  // wrap: re-stages tile 0, never read

    // stage iter it+1 — the loop's ONLY vmem ops (4 loads)
    produce_tile(srcB + nit * 8192, ringB + sp * 8192, t);

    // ---- w-production for iter it (z/az from regs)
    float wv0[8], wv1[8];
#pragma unroll
    for (int j = 0; j < 8; ++j) {
      const f32x4 zp = (j < 2) ? zc0 : (j < 4) ? zc1 : (j < 6) ? zc2 : zc3;
      const float xj = zp[(j & 1) * 2], yj = zp[(j & 1) * 2 + 1];
      const float az = (j < 4) ? az0[j] : az1[j - 4];
      const float u0 = fmaf(cX0, xj, fmaf(cY0, yj, cA0 + az));
      const float u1 = fmaf(cX1, xj, fmaf(cY1, yj, cA1 + az));
      const float ei0 = __builtin_amdgcn_exp2f(u0);
      const float ei1 = __builtin_amdgcn_exp2f(u1);
      const float s0 = ei0 * ei0, s1 = ei1 * ei1;
      const float w0 = fmaf(0.8f, s0 * s0, -ei0);  // e_E = e_I^4
      const float w1 = fmaf(0.8f, s1 * s1, -ei1);
      wv0[j] = w0; wv1[j] = w1;
      rs0 += w0; rs1 += w1;
    }
    // pack to bf16 A-fragments (truncate; R2-R4-verified)
    union { unsigned int u[4]; s16x8 v; } af0, af1;
#pragma unroll
    for (int p = 0; p < 4; ++p) {
      af0.u[p] = __builtin_amdgcn_perm(__float_as_uint(wv0[2 * p + 1]),
                                       __float_as_uint(wv0[2 * p]), 0x07060302);
      af1.u[p] = __builtin_amdgcn_perm(__float_as_uint(wv1[2 * p + 1]),
                                       __float_as_uint(wv1[2 * p]), 0x07060302);
    }
    const s16x8 a0 = af0.v, a1 = af1.v;

    // z/az prefetch for iter it+1 (LDS broadcast, lgkmcnt — not vmcnt)
    const int kn = nit * 32 + kq;
    zc0 = *(const f32x4*)(zxy + kn * 2);
    zc1 = *(const f32x4*)(zxy + kn * 2 + 4);
    zc2 = *(const f32x4*)(zxy + kn * 2 + 8);
    zc3 = *(const f32x4*)(zxy + kn * 2 + 12);
    az0 = *(const f32x4*)(zaz + kn);
    az1 = *(const f32x4*)(zaz + kn + 4);

    // drain MY half of slot it (only produce(it+1)'s 4 loads may remain),
    // then raw barrier: other wave did the same -> full slot landed. No
    // vmcnt(0) drain; produce(it+1) stays in flight.
    asm volatile("s_waitcnt vmcnt(4)\n\ts_barrier" ::: "memory");

    // ---- consume slot it: 8 B-frags via ds_read_b128, 16 MFMAs
    const char* rbl = ringB + sc * 8192 + lane * 16;
#pragma unroll
    for (int cf = 0; cf < 8; ++cf) {
      const s16x8 bfr = *(const s16x8*)(rbl + cf * 1024);
      acc0[cf] = __builtin_amdgcn_mfma_f32_16x16x32_bf16(a0, bfr, acc0[cf], 0, 0, 0);
      acc1[cf] = __builtin_amdgcn_mfma_f32_16x16x32_bf16(a1, bfr, acc1[cf], 0, 0, 0);
    }
    sc = sp;
  }

  // ---- rowsum: sum 4 quad-partials per row (lanes nf,nf+16,nf+32,nf+48)
  rs0 += __shfl_xor(rs0, 16);
  rs0 += __shfl_xor(rs0, 32);
  rs1 += __shfl_xor(rs1, 16);
  rs1 += __shfl_xor(rs1, 32);
  if (lane < 16) {
    prs[ks * NPTS + i0 + nf] = rs0;
    prs[ks * NPTS + i0 + 16 + nf] = rs1;
  }

  // ---- partial store, bf16 RNE (C/D layout: col=cf*16+nf, row=q*4+r)
  unsigned short* pb = partb + (size_t)ks * (NPTS * DH);
#pragma unroll
  for (int cf = 0; cf < 8; ++cf)
#pragma unroll
    for (int r = 0; r < 4; ++r) {
      unsigned int u0 = __float_as_uint(acc0[cf][r]);
      unsigned int u1 = __float_as_uint(acc1[cf][r]);
      u0 = (u0 + 0x7fffu + ((u0 >> 16) & 1u)) >> 16;
      u1 = (u1 + 0x7fffu + ((u1 >> 16) & 1u)) >> 16;
      pb[(i0 + q * 4 + r) * DH + cf * 16 + nf] = (unsigned short)u0;
      pb[(i0 + 16 + q * 4 + r) * DH + cf * 16 + nf] = (unsigned short)u1;
    }
}

// ---------- reduce NKS K-slice partials + normalize + scale ----------
__global__ __launch_bounds__(256) void reduce_scale(
    const unsigned short* __restrict__ partb, const float* __restrict__ prs,
    float* __restrict__ out) {
  const int gid = blockIdx.x * 256 + threadIdx.x;  // 8 cols each
  const int base = gid * 8;
  const int row = gid >> 4;
  float c[8] = {0.f, 0.f, 0.f, 0.f, 0.f, 0.f, 0.f, 0.f};
  float rsum = 0.f;
#pragma unroll
  for (int s = 0; s < NKS; ++s) {
    const u32x4 v = *(const u32x4*)(partb + (size_t)s * (NPTS * DH) + base);
#pragma unroll
    for (int i = 0; i < 4; ++i) {
      c[2 * i] += __uint_as_float(v[i] << 16);
      c[2 * i + 1] += __uint_as_float(v[i] & 0xffff0000u);
    }
    rsum += prs[s * NPTS + row];
  }
  const float scl = GAIN_C / (rsum + 1e-6f);
  f32x4 o0 = {c[0] * scl, c[1] * scl, c[2] * scl, c[3] * scl};
  f32x4 o1 = {c[4] * scl, c[5] * scl, c[6] * scl, c[7] * scl};
  *(f32x4*)(out + base) = o0;
  *(f32x4*)(out + base + 4) = o1;
}

extern "C" void kernel_launch(void* const* d_in, const int* in_sizes, int n_in,
                              void* d_out, int out_size, void* d_ws, size_t ws_size,
                              hipStream_t stream) {
  (void)in_sizes; (void)n_in; (void)out_size; (void)ws_size;
  const float* z = (const float*)d_in[0];
  const float* h = (const float*)d_in[1];
  float* out = (float*)d_out;
  unsigned short* hTf = (unsigned short*)d_ws;                          // 2 MiB
  unsigned short* partb = (unsigned short*)((char*)d_ws + (2u << 20));  // 16 MiB bf16
  float* prs = (float*)((char*)d_ws + (18u << 20));                     // 256 KiB

  h_to_hTf<<<NPTS / 32, 256, 0, stream>>>(h, hTf);
  lateral_ei_main<<<NRT * NKS, 128, 0, stream>>>(z, hTf, partb, prs);
  reduce_scale<<<(NPTS * DH / 8) / 256, 256, 0, stream>>>(partb, prs, out);
}

// Round 7
// 93.633 us; speedup vs baseline: 1.0543x; 1.0543x over previous
//
#include <hip/hip_runtime.h>

// LateralEI: out = GAIN * rownorm(K) @ h, K = 0.8*exp(-d2/0.72) - exp(-d2/2.88)
// z: [8192][2] f32, h: [8192][128] f32, out: [8192][128] f32
//
// R7 = R6 with the occupancy fix. R4 (256 blk x 8 waves) and R6 (1024 x 2)
// both ran 2048 waves = 2 waves/SIMD and both landed ~44us => latency-stall
// bound, not pipe bound. R7 runs 4096 waves (NKS=16, 4-wave blocks, grid
// 1024 = 4 blocks/CU x 16 waves/CU = 4/SIMD, launch_bounds(256,4)).
// Depth-2 8KB ring shared by 4 waves (B L2 traffic 128 MB), 2 barriers/iter:
//   produce(it+1) | compute w(it) | vmcnt(2)+bar1 | consume(it) | bar2
// bar1: own vmcnt(2) drains own produce(it) before arrival -> slot landed for
// all. bar2: all reads of slot (it+1)&1 (done in body it-1) precede anyone's
// produce(it+2) write (issued after bar2). ds_reads complete before a wave
// reaches bar2 (compiler lgkmcnt before MFMA use). Loop vmem = ONLY the 2
// produce ops/wave -> vmcnt(2) deterministic (R6-verified discipline).

typedef float f32x4 __attribute__((ext_vector_type(4)));
typedef float f32x2 __attribute__((ext_vector_type(2)));
typedef short s16x8 __attribute__((ext_vector_type(8)));
typedef unsigned int u32x4 __attribute__((ext_vector_type(4)));

#define NPTS 8192
#define DH 128
#define A_I (-0.5009357781f)  // -log2(e)/(2*1.2^2); A_E = 4*A_I
#define GAIN_C 0.05f

#define NKS 16      // cross-block K-slices (512 k each)
#define KSL 512     // k per slice
#define NITER 16    // 512 / 32
#define NRT 64      // row-tiles (128 rows each)

// ---------- pre-pass: h [8192][128] f32 -> hTf fragment-major bf16 (R4-verified) ----------
__global__ __launch_bounds__(256) void h_to_hTf(
    const float* __restrict__ h, unsigned short* __restrict__ hTf) {
  __shared__ unsigned int tileW[DH * 17];  // [n][kp], kp = k-pair 0..15
  const int t = threadIdx.x;
  const int k5 = blockIdx.x;
  const int n = t & 127;
  const int g = t >> 7;  // 0..1
#pragma unroll
  for (int p = 0; p < 8; ++p) {
    const int kp = g * 8 + p;
    unsigned int a = __float_as_uint(h[(k5 * 32 + 2 * kp) * DH + n]);
    unsigned int b = __float_as_uint(h[(k5 * 32 + 2 * kp + 1) * DH + n]);
    a = (a + 0x7fffu + ((a >> 16) & 1u)) >> 16;          // RNE low half
    b = (b + 0x7fffu + ((b >> 16) & 1u)) & 0xffff0000u;  // RNE high half
    tileW[n * 17 + kp] = a | b;
  }
  __syncthreads();
#pragma unroll
  for (int it = 0; it < 2; ++it) {
    const int u = t + it * 256;
    const int cf = u >> 6;
    const int lane = u & 63;
    const int nf = lane & 15;
    const int q = lane >> 4;
    const int n2 = cf * 16 + nf;
    u32x4 val;
#pragma unroll
    for (int i = 0; i < 4; ++i) val[i] = tileW[n2 * 17 + q * 4 + i];
    *(u32x4*)(hTf + k5 * 4096 + u * 8) = val;
  }
}

// stage one 8KB B-tile into a ring slot: 256 threads x 2 x 16B (2 instrs/wave)
__device__ __forceinline__ void produce_tile(const char* src, char* dst, int t) {
  __builtin_amdgcn_global_load_lds(
      (const __attribute__((address_space(1))) unsigned int*)(src + t * 16),
      (__attribute__((address_space(3))) unsigned int*)(dst + t * 16), 16, 0, 0);
  __builtin_amdgcn_global_load_lds(
      (const __attribute__((address_space(1))) unsigned int*)(src + 4096 + t * 16),
      (__attribute__((address_space(3))) unsigned int*)(dst + 4096 + t * 16), 16, 0, 0);
}

// ---------- main fused kernel ----------
__global__ __launch_bounds__(256, 4) void lateral_ei_main(
    const float* __restrict__ z, const unsigned short* __restrict__ hTf,
    unsigned short* __restrict__ partb, float* __restrict__ prs) {
  __shared__ __align__(16) unsigned short ring[2][4096];  // 2 x 8KB
  __shared__ __align__(16) float zxy[KSL * 2];            // 4KB (x,y) per k
  __shared__ __align__(16) float zaz[KSL];                // 2KB A_I*|z_k|^2

  const int t = threadIdx.x;
  const int lane = t & 63;
  const int w = t >> 6;  // wave 0..3
  const int rt = blockIdx.x & (NRT - 1);
  const int ks = blockIdx.x >> 6;  // 0..NKS-1
  const int i0 = rt * 128 + w * 32;
  const int nf = lane & 15;
  const int q = lane >> 4;
  const int k0 = ks * KSL;

  // zi constants for rows i0+nf, i0+16+nf
  const float zx0 = z[(i0 + nf) * 2], zy0 = z[(i0 + nf) * 2 + 1];
  const float zx1 = z[(i0 + 16 + nf) * 2], zy1 = z[(i0 + 16 + nf) * 2 + 1];
  const float cA0 = A_I * (zx0 * zx0 + zy0 * zy0);
  const float cA1 = A_I * (zx1 * zx1 + zy1 * zy1);
  const float cX0 = -2.f * A_I * zx0, cY0 = -2.f * A_I * zy0;
  const float cX1 = -2.f * A_I * zx1, cY1 = -2.f * A_I * zy1;

  const char* srcB = (const char*)hTf + (size_t)ks * (16 * 8192);
  char* ringB = (char*)&ring[0][0];

  // ---- preamble: stage slot 0; stage z/az slice (2 k per thread) ----
  produce_tile(srcB, ringB, t);
  {
    const int k2 = t * 2;
    const f32x4 p = *(const f32x4*)(z + (size_t)(k0 + k2) * 2);  // x0,y0,x1,y1
    *(f32x4*)(zxy + k2 * 2) = p;
    f32x2 az;
    az[0] = A_I * fmaf(p[1], p[1], p[0] * p[0]);
    az[1] = A_I * fmaf(p[3], p[3], p[2] * p[2]);
    *(f32x2*)(zaz + k2) = az;
  }
  __syncthreads();  // drains preamble vmem (incl. produce(0)) + LDS writes

  f32x4 acc0[8], acc1[8];
#pragma unroll
  for (int cf = 0; cf < 8; ++cf) {
    acc0[cf] = (f32x4){0.f, 0.f, 0.f, 0.f};
    acc1[cf] = (f32x4){0.f, 0.f, 0.f, 0.f};
  }
  float rs0a = 0.f, rs0b = 0.f, rs1a = 0.f, rs1b = 0.f;

#pragma unroll 1
  for (int it = 0; it < NITER; ++it) {
    const int nit = (it + 1) & (NITER - 1);  // wrap: re-stages tile 0, never read

    // stage iter it+1 — the loop's ONLY vmem ops (2 instrs/wave)
    produce_tile(srcB + nit * 8192, ringB + ((it + 1) & 1) * 8192, t);

    // ---- w-production for iter it (z/az from LDS, quad-uniform broadcast)
    const float* zp_ = zxy + it * 64 + q * 16;
    const f32x4 zcA = *(const f32x4*)(zp_ + 0);
    const f32x4 zcB = *(const f32x4*)(zp_ + 4);
    const f32x4 zcC = *(const f32x4*)(zp_ + 8);
    const f32x4 zcD = *(const f32x4*)(zp_ + 12);
    const f32x4 az0 = *(const f32x4*)(zaz + it * 32 + q * 8);
    const f32x4 az1 = *(const f32x4*)(zaz + it * 32 + q * 8 + 4);

    float wv0[8], wv1[8];
#pragma unroll
    for (int j = 0; j < 8; ++j) {
      const f32x4 zp = (j < 2) ? zcA : (j < 4) ? zcB : (j < 6) ? zcC : zcD;
      const float xj = zp[(j & 1) * 2], yj = zp[(j & 1) * 2 + 1];
      const float az = (j < 4) ? az0[j] : az1[j - 4];
      const float u0 = fmaf(cX0, xj, fmaf(cY0, yj, cA0 + az));
      const float u1 = fmaf(cX1, xj, fmaf(cY1, yj, cA1 + az));
      const float ei0 = __builtin_amdgcn_exp2f(u0);
      const float ei1 = __builtin_amdgcn_exp2f(u1);
      const float s0 = ei0 * ei0, s1 = ei1 * ei1;
      const float w0 = fmaf(0.8f, s0 * s0, -ei0);  // e_E = e_I^4
      const float w1 = fmaf(0.8f, s1 * s1, -ei1);
      wv0[j] = w0; wv1[j] = w1;
      if (j & 1) { rs0b += w0; rs1b += w1; } else { rs0a += w0; rs1a += w1; }
    }
    union { unsigned int u[4]; s16x8 v; } af0, af1;
#pragma unroll
    for (int p = 0; p < 4; ++p) {
      af0.u[p] = __builtin_amdgcn_perm(__float_as_uint(wv0[2 * p + 1]),
                                       __float_as_uint(wv0[2 * p]), 0x07060302);
      af1.u[p] = __builtin_amdgcn_perm(__float_as_uint(wv1[2 * p + 1]),
                                       __float_as_uint(wv1[2 * p]), 0x07060302);
    }
    const s16x8 a0 = af0.v, a1 = af1.v;

    // own produce(it) drained (only produce(it+1)'s 2 remain) -> bar1:
    // slot it fully landed for all 4 waves. Prefetch stays in flight.
    asm volatile("s_waitcnt vmcnt(2)\n\ts_barrier" ::: "memory");

    // ---- consume slot it: 8 B-frags via ds_read_b128, 16 MFMAs
    const char* rbl = ringB + (it & 1) * 8192 + lane * 16;
#pragma unroll
    for (int cf = 0; cf < 8; ++cf) {
      const s16x8 bfr = *(const s16x8*)(rbl + cf * 1024);
      acc0[cf] = __builtin_amdgcn_mfma_f32_16x16x32_bf16(a0, bfr, acc0[cf], 0, 0, 0);
      acc1[cf] = __builtin_amdgcn_mfma_f32_16x16x32_bf16(a1, bfr, acc1[cf], 0, 0, 0);
    }
    // bar2: depth-2 WAR — all waves' reads of slot (it&1) done before any
    // produce(it+2) (next body top) can touch it.
    asm volatile("s_barrier" ::: "memory");
  }

  // ---- rowsum: sum 4 quad-partials per row (lanes nf,nf+16,nf+32,nf+48)
  float rs0 = rs0a + rs0b, rs1 = rs1a + rs1b;
  rs0 += __shfl_xor(rs0, 16);
  rs0 += __shfl_xor(rs0, 32);
  rs1 += __shfl_xor(rs1, 16);
  rs1 += __shfl_xor(rs1, 32);
  if (lane < 16) {
    prs[ks * NPTS + i0 + nf] = rs0;
    prs[ks * NPTS + i0 + 16 + nf] = rs1;
  }

  // ---- partial store, bf16 RNE (C/D layout: col=cf*16+nf, row=q*4+r)
  unsigned short* pb = partb + (size_t)ks * (NPTS * DH);
#pragma unroll
  for (int cf = 0; cf < 8; ++cf)
#pragma unroll
    for (int r = 0; r < 4; ++r) {
      unsigned int u0 = __float_as_uint(acc0[cf][r]);
      unsigned int u1 = __float_as_uint(acc1[cf][r]);
      u0 = (u0 + 0x7fffu + ((u0 >> 16) & 1u)) >> 16;
      u1 = (u1 + 0x7fffu + ((u1 >> 16) & 1u)) >> 16;
      pb[(i0 + q * 4 + r) * DH + cf * 16 + nf] = (unsigned short)u0;
      pb[(i0 + 16 + q * 4 + r) * DH + cf * 16 + nf] = (unsigned short)u1;
    }
}

// ---------- reduce NKS K-slice partials + normalize + scale ----------
__global__ __launch_bounds__(256) void reduce_scale(
    const unsigned short* __restrict__ partb, const float* __restrict__ prs,
    float* __restrict__ out) {
  const int gid = blockIdx.x * 256 + threadIdx.x;  // 8 cols each
  const int base = gid * 8;
  const int row = gid >> 4;
  float c[8] = {0.f, 0.f, 0.f, 0.f, 0.f, 0.f, 0.f, 0.f};
  float rsum = 0.f;
#pragma unroll
  for (int s = 0; s < NKS; ++s) {
    const u32x4 v = *(const u32x4*)(partb + (size_t)s * (NPTS * DH) + base);
#pragma unroll
    for (int i = 0; i < 4; ++i) {
      c[2 * i] += __uint_as_float(v[i] << 16);
      c[2 * i + 1] += __uint_as_float(v[i] & 0xffff0000u);
    }
    rsum += prs[s * NPTS + row];
  }
  const float scl = GAIN_C / (rsum + 1e-6f);
  f32x4 o0 = {c[0] * scl, c[1] * scl, c[2] * scl, c[3] * scl};
  f32x4 o1 = {c[4] * scl, c[5] * scl, c[6] * scl, c[7] * scl};
  *(f32x4*)(out + base) = o0;
  *(f32x4*)(out + base + 4) = o1;
}

extern "C" void kernel_launch(void* const* d_in, const int* in_sizes, int n_in,
                              void* d_out, int out_size, void* d_ws, size_t ws_size,
                              hipStream_t stream) {
  (void)in_sizes; (void)n_in; (void)out_size; (void)ws_size;
  const float* z = (const float*)d_in[0];
  const float* h = (const float*)d_in[1];
  float* out = (float*)d_out;
  unsigned short* hTf = (unsigned short*)d_ws;                          // 2 MiB
  unsigned short* partb = (unsigned short*)((char*)d_ws + (2u << 20));  // 32 MiB bf16
  float* prs = (float*)((char*)d_ws + (34u << 20));                     // 512 KiB

  h_to_hTf<<<NPTS / 32, 256, 0, stream>>>(h, hTf);
  lateral_ei_main<<<NRT * NKS, 256, 0, stream>>>(z, hTf, partb, prs);
  reduce_scale<<<(NPTS * DH / 8) / 256, 256, 0, stream>>>(partb, prs, out);
}